// Round 9
// baseline (130.823 us; speedup 1.0000x reference)
//
#include <hip/hip_runtime.h>

typedef __attribute__((ext_vector_type(8))) short short8;
typedef __attribute__((ext_vector_type(4))) float f32x4;
typedef unsigned int u32;

#define NB 64
#define NC 3
#define NH 384
#define NW 384
#define HW (NH*NW)
#define NPATCH 576
#define NE 768
#define KDIM 768           // NC*16*16
#define MDIM (NB*NPATCH)   // 36864

#define BM 128
#define NBLK_M (MDIM / BM)     // 288
#define NWG (NBLK_M * 3)       // 864  (BN=256 -> 3 n-blocks)

// two-pass tile images (BK=32 K-steps, fragment order)
#define AKK 24                 // K-steps
#define ATILE 8192             // 128 rows x 32 k x 2B
#define BTILE 16384            // 256 rows x 32 k x 2B
#define WS_A ((size_t)NBLK_M * AKK * ATILE)   // 56,623,104
#define WS_B ((size_t)3 * AKK * BTILE)        // 1,179,648

#define GLOBAL_AS __attribute__((address_space(1)))
#define LDS_AS    __attribute__((address_space(3)))

__device__ __forceinline__ unsigned short f2bf(float f) {
    unsigned int u = __builtin_bit_cast(unsigned int, f);
    u += 0x7fffu + ((u >> 16) & 1u);   // round-to-nearest-even
    return (unsigned short)(u >> 16);
}

// packed f32x2 -> bf16x2 (RNE), 1 VALU inst (no builtin on gfx950)
__device__ __forceinline__ u32 cvtpk(float lo, float hi) {
    u32 r;
    asm("v_cvt_pk_bf16_f32 %0, %1, %2" : "=v"(r) : "v"(lo), "v"(hi));
    return r;
}

__device__ __forceinline__ void gload_lds16(const void* g, void* l) {
    __builtin_amdgcn_global_load_lds((const GLOBAL_AS u32*)g, (LDS_AS u32*)l, 16, 0, 0);
}

// =====================================================================
// PASS 1 (merged): gather patches -> bf16 A FRAGMENT-ORDER tiles, and
// proj_w -> bf16 B FRAGMENT-ORDER tiles.
// A tile (bm,kk) = 8KB: frag fa = wr*4+mi (1KB each), lane l = lk*16+lr
//   holds A[row = wr*64+mi*16+lr][k = kk*32 + lk*8 .. +8].
// B tile (bn,kk) = 16KB: frag g (0..15), lane l holds
//   pw[e = bn*256+g*16+(l&15)][k = kk*32 + (l>>4)*8 .. +8].
// =====================================================================
#define GATHER_BLOCKS (MDIM * 96 / 256)   // 13824
__global__ __launch_bounds__(256) void prep(
    const float* __restrict__ x,
    const int* __restrict__ start_h,
    const int* __restrict__ start_w,
    const float* __restrict__ pw,
    unsigned char* __restrict__ wsa,
    unsigned char* __restrict__ wsb)
{
    const int gid = blockIdx.x;
    if (gid < GATHER_BLOCKS) {
        int id = gid * 256 + threadIdx.x;
        int m  = id / 96;
        int ck = id - m * 96;          // 8-wide k-chunk 0..95
        int b  = m / NPATCH;
        int n  = m - b * NPATCH;
        int base = b * (NC * HW) + start_h[b * NPATCH + n] * NW
                 + start_w[b * NPATCH + n];
        int gk = ck * 8;               // k = c*256 + h*16 + w
        int c  = gk >> 8;
        int h  = (gk & 255) >> 4;
        int w  = gk & 15;              // 0 or 8
        const float* src = x + base + c * HW + h * NW + w;
        float4 f0 = *reinterpret_cast<const float4*>(src);
        float4 f1 = *reinterpret_cast<const float4*>(src + 4);

        int bm = m >> 7, r = m & 127;
        int kk = gk >> 5;              // 0..23
        int lk = (gk >> 3) & 3;        // 0..3
        int wr = r >> 6, mi = (r >> 4) & 3, lr = r & 15;
        size_t off = (size_t)(bm * AKK + kk) * ATILE
                   + (wr * 4 + mi) * 1024 + (lk * 16 + lr) * 16;
        *reinterpret_cast<uint4*>(wsa + off) = make_uint4(
            cvtpk(f0.x, f0.y), cvtpk(f0.z, f0.w),
            cvtpk(f1.x, f1.y), cvtpk(f1.z, f1.w));
    } else {
        int id = (gid - GATHER_BLOCKS) * 256 + threadIdx.x;  // 72*1024 = 73728
        int tile = id >> 10;           // bn*AKK + kk
        int s    = id & 1023;
        int bn = tile / AKK;
        int kk = tile - bn * AKK;
        int g = s >> 6, l = s & 63;
        int e = bn * 256 + g * 16 + (l & 15);
        int k = kk * 32 + (l >> 4) * 8;
        const float4 f0 = *reinterpret_cast<const float4*>(pw + (size_t)e * KDIM + k);
        const float4 f1 = *reinterpret_cast<const float4*>(pw + (size_t)e * KDIM + k + 4);
        *reinterpret_cast<uint4*>(wsb + (size_t)tile * BTILE + s * 16) =
            make_uint4(cvtpk(f0.x, f0.y), cvtpk(f0.z, f0.w),
                       cvtpk(f1.x, f1.y), cvtpk(f1.z, f1.w));
    }
}

// =====================================================================
// PASS 2: barrier-free, LDS-free register GEMM. Both operands read as
// coalesced 16B fragment loads (SGPR base + imm offsets); register
// double-buffer, ~1-step lookahead; compiler-counted vmcnt only.
// =====================================================================
__global__ __launch_bounds__(512, 2) void gemm_reg(
    const unsigned char* __restrict__ wsa,
    const unsigned char* __restrict__ wsb,
    const float* __restrict__ pb,
    float* __restrict__ out)
{
    const int tid = threadIdx.x;
    const int bid  = blockIdx.x;
    const int lbid = (bid & 7) * (NWG / 8) + (bid >> 3);   // XCD swizzle
    const int bm = lbid / 3;
    const int bn = lbid - bm * 3;
    const int m0 = bm * BM;
    const int e0 = bn * 256;

    const int lane = tid & 63;
    const int wv   = tid >> 6;       // 0..7
    const int wr   = wv >> 2;        // 0..1 (64 m-rows)
    const int wc   = wv & 3;         // 0..3 (64 e-cols)
    const int lr   = lane & 15;
    const int lk   = lane >> 4;      // 0..3

    const unsigned char* aB = wsa + (size_t)bm * (AKK * ATILE)
                            + (wr * 4) * 1024 + lane * 16;
    const unsigned char* bB = wsb + (size_t)bn * (AKK * BTILE)
                            + (wc * 4) * 1024 + lane * 16;

    f32x4 acc[4][4] = {};
    uint4 a0[4], b0[4], a1[4], b1[4];

#define LOADS(KK, AR, BR)                                                     \
    {                                                                         \
        _Pragma("unroll")                                                     \
        for (int mi = 0; mi < 4; ++mi)                                        \
            AR[mi] = *reinterpret_cast<const uint4*>(                         \
                aB + (KK) * ATILE + mi * 1024);                               \
        _Pragma("unroll")                                                     \
        for (int ni = 0; ni < 4; ++ni)                                        \
            BR[ni] = *reinterpret_cast<const uint4*>(                         \
                bB + (KK) * BTILE + ni * 1024);                               \
    }

#define STEP(AR, BR)                                                          \
    {                                                                         \
        _Pragma("unroll")                                                     \
        for (int mi = 0; mi < 4; ++mi)                                        \
            _Pragma("unroll")                                                 \
            for (int ni = 0; ni < 4; ++ni)                                    \
                acc[mi][ni] = __builtin_amdgcn_mfma_f32_16x16x32_bf16(        \
                    __builtin_bit_cast(short8, AR[mi]),                       \
                    __builtin_bit_cast(short8, BR[ni]),                       \
                    acc[mi][ni], 0, 0, 0);                                    \
    }

    LOADS(0, a0, b0)
    LOADS(1, a1, b1)
    #pragma unroll 1
    for (int kk = 0; kk < AKK; kk += 2) {
        STEP(a0, b0)
        if (kk + 2 < AKK) LOADS(kk + 2, a0, b0)
        STEP(a1, b1)
        if (kk + 3 < AKK) LOADS(kk + 3, a1, b1)
    }

#undef LOADS
#undef STEP

    // ---- epilogue: bias + store ----
    float biasv[4];
    #pragma unroll
    for (int ni = 0; ni < 4; ++ni)
        biasv[ni] = pb[e0 + wc * 64 + ni * 16 + lr];

    #pragma unroll
    for (int mi = 0; mi < 4; ++mi) {
        #pragma unroll
        for (int j = 0; j < 4; ++j) {
            int row = m0 + wr * 64 + mi * 16 + lk * 4 + j;
            float* orow = out + (size_t)row * NE + e0 + wc * 64 + lr;
            #pragma unroll
            for (int ni = 0; ni < 4; ++ni)
                orow[ni * 16] = acc[mi][ni][j] + biasv[ni];
        }
    }
}

// =====================================================================
// FALLBACK (ws too small for two-pass): R6 fused kernel (78 us proven).
// Own constants: BK=64, 12 K-steps, B row-tiles of 32KB.
// =====================================================================
__global__ __launch_bounds__(256) void convert_w_row(
    const float* __restrict__ pw, unsigned char* __restrict__ wsb)
{
    int id = blockIdx.x * 256 + threadIdx.x;   // 768*96 = 73728
    int e  = id / 96;
    int ck = id - e * 96;
    int k0 = ck * 8;

    const float4 f0 = *reinterpret_cast<const float4*>(pw + (size_t)e * KDIM + k0);
    const float4 f1 = *reinterpret_cast<const float4*>(pw + (size_t)e * KDIM + k0 + 4);
    int bn = e >> 8;
    int r  = e & 255;
    int kk = k0 >> 6;
    int ch = (k0 & 63) >> 3;
    size_t off = (size_t)(bn * 12 + kk) * 32768 + r * 128
               + ((ch ^ (r & 7)) * 16);
    *reinterpret_cast<uint4*>(wsb + off) = make_uint4(
        cvtpk(f0.x, f0.y), cvtpk(f0.z, f0.w),
        cvtpk(f1.x, f1.y), cvtpk(f1.z, f1.w));
}

template <bool WSB>
__global__ __launch_bounds__(512, 4) void fused_gemm(
    const float* __restrict__ x,
    const int* __restrict__ start_h,
    const int* __restrict__ start_w,
    const float* __restrict__ pw,
    const float* __restrict__ pb,
    const unsigned char* __restrict__ wsb,
    float* __restrict__ out)
{
    __shared__ __align__(16) unsigned short lA[2][BM * 64];
    __shared__ __align__(16) unsigned short lB[256 * 64];
    __shared__ int baseOff[BM];

    const int tid = threadIdx.x;
    const int bid  = blockIdx.x;
    const int lbid = (bid & 7) * (NWG / 8) + (bid >> 3);
    const int bm = lbid / 3;
    const int bn = lbid - bm * 3;
    const int m0 = bm * BM;
    const int e0 = bn * 256;

    if (tid < BM) {
        int m = m0 + tid;
        int b = m / NPATCH;
        int n = m - b * NPATCH;
        baseOff[tid] = b * (NC * HW) + start_h[b * NPATCH + n] * NW
                     + start_w[b * NPATCH + n];
    }

    const int lane = tid & 63;
    const int wv   = tid >> 6;
    const int wr   = wv >> 2;
    const int wc   = wv & 3;
    const int lr   = lane & 15;
    const int lk   = lane >> 4;

    const int rt = tid >> 4;
    const int j0 = (tid & 15) * 4;
    const int chunk  = j0 >> 3;
    const int within = j0 & 7;
    const int hsub   = j0 >> 4;
    const int wsub   = j0 & 15;

    __syncthreads();

    int ab[4];
    #pragma unroll
    for (int i = 0; i < 4; ++i)
        ab[i] = baseOff[i * 32 + rt] + hsub * NW + wsub;

    f32x4 acc[4][4] = {};
    float4 ar[4];

#define LOADA(KK)                                                             \
    {                                                                         \
        const int koff = ((KK) >> 2) * HW + ((KK) & 3) * 4 * NW;              \
        _Pragma("unroll")                                                     \
        for (int i = 0; i < 4; ++i)                                           \
            ar[i] = *reinterpret_cast<const float4*>(x + ab[i] + koff);       \
    }

#define WRITEA(BUF)                                                           \
    {                                                                         \
        _Pragma("unroll")                                                     \
        for (int i = 0; i < 4; ++i) {                                         \
            int r = i * 32 + rt;                                              \
            int off = r * 64 + ((chunk ^ (r & 7)) * 8) + within;              \
            *reinterpret_cast<uint2*>(&lA[BUF][off]) =                        \
                make_uint2(cvtpk(ar[i].x, ar[i].y), cvtpk(ar[i].z, ar[i].w)); \
        }                                                                     \
    }

#define STAGEB(KK)                                                            \
    if (WSB) {                                                                \
        const unsigned char* src = wsb + (size_t)(bn * 12 + (KK)) * 32768     \
                                 + wv * 1024 + lane * 16;                     \
        unsigned char* dst = reinterpret_cast<unsigned char*>(lB) + wv * 1024;\
        _Pragma("unroll")                                                     \
        for (int i = 0; i < 4; ++i)                                           \
            gload_lds16(src + i * 8192, dst + i * 8192);                      \
    } else {                                                                  \
        _Pragma("unroll")                                                     \
        for (int i = 0; i < 8; ++i) {                                         \
            int r = i * 32 + rt;                                              \
            const float4 wf = *reinterpret_cast<const float4*>(               \
                pw + (size_t)(e0 + r) * KDIM + (KK) * 64 + j0);               \
            int off = r * 64 + ((chunk ^ (r & 7)) * 8) + within;              \
            *reinterpret_cast<uint2*>(&lB[off]) =                            \
                make_uint2(cvtpk(wf.x, wf.y), cvtpk(wf.z, wf.w));             \
        }                                                                     \
    }

#define COMPUTE(BUF)                                                          \
    {                                                                         \
        _Pragma("unroll")                                                     \
        for (int ks = 0; ks < 2; ++ks) {                                      \
            short8 af[4], bfr[4];                                             \
            _Pragma("unroll")                                                 \
            for (int mi = 0; mi < 4; ++mi) {                                  \
                int row = wr * 64 + mi * 16 + lr;                             \
                int off = row * 64 + (((ks * 4 + lk) ^ (row & 7)) * 8);       \
                af[mi] = *reinterpret_cast<const short8*>(&lA[BUF][off]);     \
            }                                                                 \
            _Pragma("unroll")                                                 \
            for (int ni = 0; ni < 4; ++ni) {                                  \
                int row = wc * 64 + ni * 16 + lr;                             \
                int off = row * 64 + (((ks * 4 + lk) ^ (row & 7)) * 8);       \
                bfr[ni] = *reinterpret_cast<const short8*>(&lB[off]);         \
            }                                                                 \
            _Pragma("unroll")                                                 \
            for (int mi = 0; mi < 4; ++mi)                                    \
                _Pragma("unroll")                                             \
                for (int ni = 0; ni < 4; ++ni)                                \
                    acc[mi][ni] = __builtin_amdgcn_mfma_f32_16x16x32_bf16(    \
                        af[mi], bfr[ni], acc[mi][ni], 0, 0, 0);               \
        }                                                                     \
    }

    LOADA(0)
    WRITEA(0)
    STAGEB(0)
    __syncthreads();

    for (int kk = 0; kk < 12; ++kk) {
        const int buf = kk & 1;
        if (kk + 1 < 12) LOADA(kk + 1)
        COMPUTE(buf)
        __syncthreads();
        if (kk + 1 < 12) {
            WRITEA(buf ^ 1)
            STAGEB(kk + 1)
        }
        __syncthreads();
    }

#undef LOADA
#undef WRITEA
#undef STAGEB
#undef COMPUTE

    float biasv[4];
    #pragma unroll
    for (int ni = 0; ni < 4; ++ni)
        biasv[ni] = pb[e0 + wc * 64 + ni * 16 + lr];

    #pragma unroll
    for (int mi = 0; mi < 4; ++mi) {
        #pragma unroll
        for (int j = 0; j < 4; ++j) {
            int row = m0 + wr * 64 + mi * 16 + lk * 4 + j;
            float* orow = out + (size_t)row * NE + e0 + wc * 64 + lr;
            #pragma unroll
            for (int ni = 0; ni < 4; ++ni)
                orow[ni * 16] = acc[mi][ni][j] + biasv[ni];
        }
    }
}

extern "C" void kernel_launch(void* const* d_in, const int* in_sizes, int n_in,
                              void* d_out, int out_size, void* d_ws, size_t ws_size,
                              hipStream_t stream) {
    const float* x  = (const float*)d_in[0];
    const int* sh   = (const int*)d_in[1];
    const int* sw   = (const int*)d_in[2];
    const float* pw = (const float*)d_in[3];
    const float* pb = (const float*)d_in[4];
    float* out = (float*)d_out;

    if (ws_size >= WS_A + WS_B) {
        unsigned char* wsa = (unsigned char*)d_ws;
        unsigned char* wsb = wsa + WS_A;
        hipLaunchKernelGGL(prep, dim3(GATHER_BLOCKS + 288), dim3(256), 0, stream,
                           x, sh, sw, pw, wsa, wsb);
        hipLaunchKernelGGL(gemm_reg, dim3(NWG), dim3(512), 0, stream,
                           wsa, wsb, pb, out);
    } else if (ws_size >= (size_t)1179648) {
        unsigned char* wsb = (unsigned char*)d_ws;
        hipLaunchKernelGGL(convert_w_row, dim3(288), dim3(256), 0, stream, pw, wsb);
        hipLaunchKernelGGL(fused_gemm<true>, dim3(NWG), dim3(512), 0, stream,
                           x, sh, sw, pw, pb, wsb, out);
    } else {
        hipLaunchKernelGGL(fused_gemm<false>, dim3(NWG), dim3(512), 0, stream,
                           x, sh, sw, pw, pb, (const unsigned char*)nullptr, out);
    }
}

// Round 10
// 114.003 us; speedup vs baseline: 1.1475x; 1.1475x over previous
//
#include <hip/hip_runtime.h>

typedef __attribute__((ext_vector_type(8))) short short8;
typedef __attribute__((ext_vector_type(4))) float f32x4;
typedef unsigned int u32;

#define NB 64
#define NC 3
#define NH 384
#define NW 384
#define HW (NH*NW)
#define NPATCH 576
#define NE 768
#define KDIM 768           // NC*16*16
#define MDIM (NB*NPATCH)   // 36864

#define BM 128
#define NBLK_M (MDIM / BM)     // 288
#define NWG (NBLK_M * 3)       // 864  (BN=256 -> 3 n-blocks)

// two-pass tile images (BK=32 K-steps, fragment order)
#define AKK 24                 // K-steps
#define ATILE 8192             // 128 rows x 32 k x 2B
#define BTILE 16384            // 256 rows x 32 k x 2B
#define WS_A ((size_t)NBLK_M * AKK * ATILE)   // 56,623,104
#define WS_B ((size_t)3 * AKK * BTILE)        // 1,179,648

// prep v2: write-linear slot mapping, J=4 chains/thread
#define SLOTS (NBLK_M * AKK * 512)     // 3,538,944 16B-slots of wsa
#define PREP_J 4
#define PREP_STRIDE (SLOTS / PREP_J)   // 884,736
#define PREP_BLOCKS (PREP_STRIDE / 256) // 3456

#define GLOBAL_AS __attribute__((address_space(1)))
#define LDS_AS    __attribute__((address_space(3)))

__device__ __forceinline__ unsigned short f2bf(float f) {
    unsigned int u = __builtin_bit_cast(unsigned int, f);
    u += 0x7fffu + ((u >> 16) & 1u);   // round-to-nearest-even
    return (unsigned short)(u >> 16);
}

// packed f32x2 -> bf16x2 (RNE), 1 VALU inst (no builtin on gfx950)
__device__ __forceinline__ u32 cvtpk(float lo, float hi) {
    u32 r;
    asm("v_cvt_pk_bf16_f32 %0, %1, %2" : "=v"(r) : "v"(lo), "v"(hi));
    return r;
}

__device__ __forceinline__ void gload_lds16(const void* g, void* l) {
    __builtin_amdgcn_global_load_lds((const GLOBAL_AS u32*)g, (LDS_AS u32*)l, 16, 0, 0);
}

// =====================================================================
// PASS 1: gather -> A fragment-order tiles (write-linear, 4 chains) and
// proj_w -> B fragment-order tiles.
// A slot sid (16B): tile = sid>>9 (bm*24+kk), s = sid&511:
//   frag = s>>6 (= wr*4+mi), l = s&63 (= lk*16+lr);
//   holds A[m = bm*128 + (frag>>2)*64 + (frag&3)*16 + (l&15)]
//          [k = kk*32 + (l>>4)*8 .. +8]  as 8 bf16.
// =====================================================================
__global__ __launch_bounds__(256) void prep(
    const float* __restrict__ x,
    const int* __restrict__ start_h,
    const int* __restrict__ start_w,
    const float* __restrict__ pw,
    unsigned char* __restrict__ wsa,
    unsigned char* __restrict__ wsb)
{
    const int gid = blockIdx.x;
    if (gid < PREP_BLOCKS) {
        const int t0 = gid * 256 + threadIdx.x;
        float4 f[PREP_J][2];
        // issue all 8 x-loads (4 independent chains) before any conversion
        #pragma unroll
        for (int j = 0; j < PREP_J; ++j) {
            int sid = t0 + j * PREP_STRIDE;
            int tile = sid >> 9;
            int s    = sid & 511;
            int bm = tile / AKK;
            int kk = tile - bm * AKK;
            int frag = s >> 6, l = s & 63;
            int lk = l >> 4, lr = l & 15;
            int r  = (frag >> 2) * 64 + (frag & 3) * 16 + lr;
            int m  = bm * 128 + r;
            int b  = m / NPATCH;
            int n  = m - b * NPATCH;
            int base = b * (NC * HW) + start_h[b * NPATCH + n] * NW
                     + start_w[b * NPATCH + n];
            int gk = kk * 32 + lk * 8;       // k = c*256 + h*16 + w
            int c  = gk >> 8;
            int h  = (gk >> 4) & 15;
            int w  = gk & 15;                // 0 or 8
            const float* src = x + base + c * HW + h * NW + w;
            f[j][0] = *reinterpret_cast<const float4*>(src);
            f[j][1] = *reinterpret_cast<const float4*>(src + 4);
        }
        // coalesced 16B writes (wave = contiguous 1KB per j)
        #pragma unroll
        for (int j = 0; j < PREP_J; ++j) {
            int sid = t0 + j * PREP_STRIDE;
            *reinterpret_cast<uint4*>(wsa + (size_t)sid * 16) = make_uint4(
                cvtpk(f[j][0].x, f[j][0].y), cvtpk(f[j][0].z, f[j][0].w),
                cvtpk(f[j][1].x, f[j][1].y), cvtpk(f[j][1].z, f[j][1].w));
        }
    } else {
        int id = (gid - PREP_BLOCKS) * 256 + threadIdx.x;  // 72*1024 = 73728
        int tile = id >> 10;           // bn*AKK + kk
        int s    = id & 1023;
        int bn = tile / AKK;
        int kk = tile - bn * AKK;
        int g = s >> 6, l = s & 63;
        int e = bn * 256 + g * 16 + (l & 15);
        int k = kk * 32 + (l >> 4) * 8;
        const float4 f0 = *reinterpret_cast<const float4*>(pw + (size_t)e * KDIM + k);
        const float4 f1 = *reinterpret_cast<const float4*>(pw + (size_t)e * KDIM + k + 4);
        *reinterpret_cast<uint4*>(wsb + (size_t)tile * BTILE + s * 16) =
            make_uint4(cvtpk(f0.x, f0.y), cvtpk(f0.z, f0.w),
                       cvtpk(f1.x, f1.y), cvtpk(f1.z, f1.w));
    }
}

// =====================================================================
// PASS 2: barrier-free, LDS-free register GEMM, prefetch DEPTH 3.
// Both operands read as coalesced 16B fragment loads; compiler-counted
// vmcnt only; load->use distance = 2 full MFMA steps.
// =====================================================================
__global__ __launch_bounds__(512) void gemm_reg(
    const unsigned char* __restrict__ wsa,
    const unsigned char* __restrict__ wsb,
    const float* __restrict__ pb,
    float* __restrict__ out)
{
    const int tid = threadIdx.x;
    const int bid  = blockIdx.x;
    const int lbid = (bid & 7) * (NWG / 8) + (bid >> 3);   // XCD swizzle
    const int bm = lbid / 3;
    const int bn = lbid - bm * 3;
    const int m0 = bm * BM;
    const int e0 = bn * 256;

    const int lane = tid & 63;
    const int wv   = tid >> 6;       // 0..7
    const int wr   = wv >> 2;        // 0..1 (64 m-rows)
    const int wc   = wv & 3;         // 0..3 (64 e-cols)
    const int lr   = lane & 15;
    const int lk   = lane >> 4;      // 0..3

    const unsigned char* aB = wsa + (size_t)bm * (AKK * ATILE)
                            + (wr * 4) * 1024 + lane * 16;
    const unsigned char* bB = wsb + (size_t)bn * (AKK * BTILE)
                            + (wc * 4) * 1024 + lane * 16;

    f32x4 acc[4][4] = {};
    uint4 a0[4], b0[4], a1[4], b1[4], a2[4], b2[4];

#define LOADS(KK, AR, BR)                                                     \
    {                                                                         \
        _Pragma("unroll")                                                     \
        for (int mi = 0; mi < 4; ++mi)                                        \
            AR[mi] = *reinterpret_cast<const uint4*>(                         \
                aB + (KK) * ATILE + mi * 1024);                               \
        _Pragma("unroll")                                                     \
        for (int ni = 0; ni < 4; ++ni)                                        \
            BR[ni] = *reinterpret_cast<const uint4*>(                         \
                bB + (KK) * BTILE + ni * 1024);                               \
    }

#define STEP(AR, BR)                                                          \
    {                                                                         \
        _Pragma("unroll")                                                     \
        for (int mi = 0; mi < 4; ++mi)                                        \
            _Pragma("unroll")                                                 \
            for (int ni = 0; ni < 4; ++ni)                                    \
                acc[mi][ni] = __builtin_amdgcn_mfma_f32_16x16x32_bf16(        \
                    __builtin_bit_cast(short8, AR[mi]),                       \
                    __builtin_bit_cast(short8, BR[ni]),                       \
                    acc[mi][ni], 0, 0, 0);                                    \
    }

    LOADS(0, a0, b0)
    LOADS(1, a1, b1)
    LOADS(2, a2, b2)
    #pragma unroll 1
    for (int kk = 0; kk < AKK; kk += 3) {       // 24 steps = 8 iterations
        STEP(a0, b0)
        if (kk + 3 < AKK) LOADS(kk + 3, a0, b0)
        STEP(a1, b1)
        if (kk + 4 < AKK) LOADS(kk + 4, a1, b1)
        STEP(a2, b2)
        if (kk + 5 < AKK) LOADS(kk + 5, a2, b2)
    }

#undef LOADS
#undef STEP

    // ---- epilogue: bias + store ----
    float biasv[4];
    #pragma unroll
    for (int ni = 0; ni < 4; ++ni)
        biasv[ni] = pb[e0 + wc * 64 + ni * 16 + lr];

    #pragma unroll
    for (int mi = 0; mi < 4; ++mi) {
        #pragma unroll
        for (int j = 0; j < 4; ++j) {
            int row = m0 + wr * 64 + mi * 16 + lk * 4 + j;
            float* orow = out + (size_t)row * NE + e0 + wc * 64 + lr;
            #pragma unroll
            for (int ni = 0; ni < 4; ++ni)
                orow[ni * 16] = acc[mi][ni][j] + biasv[ni];
        }
    }
}

// =====================================================================
// FALLBACK (ws too small for two-pass): R6 fused kernel (78 us proven).
// =====================================================================
__global__ __launch_bounds__(256) void convert_w_row(
    const float* __restrict__ pw, unsigned char* __restrict__ wsb)
{
    int id = blockIdx.x * 256 + threadIdx.x;   // 768*96 = 73728
    int e  = id / 96;
    int ck = id - e * 96;
    int k0 = ck * 8;

    const float4 f0 = *reinterpret_cast<const float4*>(pw + (size_t)e * KDIM + k0);
    const float4 f1 = *reinterpret_cast<const float4*>(pw + (size_t)e * KDIM + k0 + 4);
    int bn = e >> 8;
    int r  = e & 255;
    int kk = k0 >> 6;
    int ch = (k0 & 63) >> 3;
    size_t off = (size_t)(bn * 12 + kk) * 32768 + r * 128
               + ((ch ^ (r & 7)) * 16);
    *reinterpret_cast<uint4*>(wsb + off) = make_uint4(
        cvtpk(f0.x, f0.y), cvtpk(f0.z, f0.w),
        cvtpk(f1.x, f1.y), cvtpk(f1.z, f1.w));
}

template <bool WSB>
__global__ __launch_bounds__(512, 4) void fused_gemm(
    const float* __restrict__ x,
    const int* __restrict__ start_h,
    const int* __restrict__ start_w,
    const float* __restrict__ pw,
    const float* __restrict__ pb,
    const unsigned char* __restrict__ wsb,
    float* __restrict__ out)
{
    __shared__ __align__(16) unsigned short lA[2][BM * 64];
    __shared__ __align__(16) unsigned short lB[256 * 64];
    __shared__ int baseOff[BM];

    const int tid = threadIdx.x;
    const int bid  = blockIdx.x;
    const int lbid = (bid & 7) * (NWG / 8) + (bid >> 3);
    const int bm = lbid / 3;
    const int bn = lbid - bm * 3;
    const int m0 = bm * BM;
    const int e0 = bn * 256;

    if (tid < BM) {
        int m = m0 + tid;
        int b = m / NPATCH;
        int n = m - b * NPATCH;
        baseOff[tid] = b * (NC * HW) + start_h[b * NPATCH + n] * NW
                     + start_w[b * NPATCH + n];
    }

    const int lane = tid & 63;
    const int wv   = tid >> 6;
    const int wr   = wv >> 2;
    const int wc   = wv & 3;
    const int lr   = lane & 15;
    const int lk   = lane >> 4;

    const int rt = tid >> 4;
    const int j0 = (tid & 15) * 4;
    const int chunk  = j0 >> 3;
    const int within = j0 & 7;
    const int hsub   = j0 >> 4;
    const int wsub   = j0 & 15;

    __syncthreads();

    int ab[4];
    #pragma unroll
    for (int i = 0; i < 4; ++i)
        ab[i] = baseOff[i * 32 + rt] + hsub * NW + wsub;

    f32x4 acc[4][4] = {};
    float4 ar[4];

#define LOADA(KK)                                                             \
    {                                                                         \
        const int koff = ((KK) >> 2) * HW + ((KK) & 3) * 4 * NW;              \
        _Pragma("unroll")                                                     \
        for (int i = 0; i < 4; ++i)                                           \
            ar[i] = *reinterpret_cast<const float4*>(x + ab[i] + koff);       \
    }

#define WRITEA(BUF)                                                           \
    {                                                                         \
        _Pragma("unroll")                                                     \
        for (int i = 0; i < 4; ++i) {                                         \
            int r = i * 32 + rt;                                              \
            int off = r * 64 + ((chunk ^ (r & 7)) * 8) + within;              \
            *reinterpret_cast<uint2*>(&lA[BUF][off]) =                        \
                make_uint2(cvtpk(ar[i].x, ar[i].y), cvtpk(ar[i].z, ar[i].w)); \
        }                                                                     \
    }

#define STAGEB(KK)                                                            \
    if (WSB) {                                                                \
        const unsigned char* src = wsb + (size_t)(bn * 12 + (KK)) * 32768     \
                                 + wv * 1024 + lane * 16;                     \
        unsigned char* dst = reinterpret_cast<unsigned char*>(lB) + wv * 1024;\
        _Pragma("unroll")                                                     \
        for (int i = 0; i < 4; ++i)                                           \
            gload_lds16(src + i * 8192, dst + i * 8192);                      \
    } else {                                                                  \
        _Pragma("unroll")                                                     \
        for (int i = 0; i < 8; ++i) {                                         \
            int r = i * 32 + rt;                                              \
            const float4 wf = *reinterpret_cast<const float4*>(               \
                pw + (size_t)(e0 + r) * KDIM + (KK) * 64 + j0);               \
            int off = r * 64 + ((chunk ^ (r & 7)) * 8) + within;              \
            *reinterpret_cast<uint2*>(&lB[off]) =                            \
                make_uint2(cvtpk(wf.x, wf.y), cvtpk(wf.z, wf.w));             \
        }                                                                     \
    }

#define COMPUTE(BUF)                                                          \
    {                                                                         \
        _Pragma("unroll")                                                     \
        for (int ks = 0; ks < 2; ++ks) {                                      \
            short8 af[4], bfr[4];                                             \
            _Pragma("unroll")                                                 \
            for (int mi = 0; mi < 4; ++mi) {                                  \
                int row = wr * 64 + mi * 16 + lr;                             \
                int off = row * 64 + (((ks * 4 + lk) ^ (row & 7)) * 8);       \
                af[mi] = *reinterpret_cast<const short8*>(&lA[BUF][off]);     \
            }                                                                 \
            _Pragma("unroll")                                                 \
            for (int ni = 0; ni < 4; ++ni) {                                  \
                int row = wc * 64 + ni * 16 + lr;                             \
                int off = row * 64 + (((ks * 4 + lk) ^ (row & 7)) * 8);       \
                bfr[ni] = *reinterpret_cast<const short8*>(&lB[off]);         \
            }                                                                 \
            _Pragma("unroll")                                                 \
            for (int mi = 0; mi < 4; ++mi)                                    \
                _Pragma("unroll")                                             \
                for (int ni = 0; ni < 4; ++ni)                                \
                    acc[mi][ni] = __builtin_amdgcn_mfma_f32_16x16x32_bf16(    \
                        af[mi], bfr[ni], acc[mi][ni], 0, 0, 0);               \
        }                                                                     \
    }

    LOADA(0)
    WRITEA(0)
    STAGEB(0)
    __syncthreads();

    for (int kk = 0; kk < 12; ++kk) {
        const int buf = kk & 1;
        if (kk + 1 < 12) LOADA(kk + 1)
        COMPUTE(buf)
        __syncthreads();
        if (kk + 1 < 12) {
            WRITEA(buf ^ 1)
            STAGEB(kk + 1)
        }
        __syncthreads();
    }

#undef LOADA
#undef WRITEA
#undef STAGEB
#undef COMPUTE

    float biasv[4];
    #pragma unroll
    for (int ni = 0; ni < 4; ++ni)
        biasv[ni] = pb[e0 + wc * 64 + ni * 16 + lr];

    #pragma unroll
    for (int mi = 0; mi < 4; ++mi) {
        #pragma unroll
        for (int j = 0; j < 4; ++j) {
            int row = m0 + wr * 64 + mi * 16 + lk * 4 + j;
            float* orow = out + (size_t)row * NE + e0 + wc * 64 + lr;
            #pragma unroll
            for (int ni = 0; ni < 4; ++ni)
                orow[ni * 16] = acc[mi][ni][j] + biasv[ni];
        }
    }
}

extern "C" void kernel_launch(void* const* d_in, const int* in_sizes, int n_in,
                              void* d_out, int out_size, void* d_ws, size_t ws_size,
                              hipStream_t stream) {
    const float* x  = (const float*)d_in[0];
    const int* sh   = (const int*)d_in[1];
    const int* sw   = (const int*)d_in[2];
    const float* pw = (const float*)d_in[3];
    const float* pb = (const float*)d_in[4];
    float* out = (float*)d_out;

    if (ws_size >= WS_A + WS_B) {
        unsigned char* wsa = (unsigned char*)d_ws;
        unsigned char* wsb = wsa + WS_A;
        hipLaunchKernelGGL(prep, dim3(PREP_BLOCKS + 288), dim3(256), 0, stream,
                           x, sh, sw, pw, wsa, wsb);
        hipLaunchKernelGGL(gemm_reg, dim3(NWG), dim3(512), 0, stream,
                           wsa, wsb, pb, out);
    } else if (ws_size >= (size_t)1179648) {
        unsigned char* wsb = (unsigned char*)d_ws;
        hipLaunchKernelGGL(convert_w_row, dim3(288), dim3(256), 0, stream, pw, wsb);
        hipLaunchKernelGGL(fused_gemm<true>, dim3(NWG), dim3(512), 0, stream,
                           x, sh, sw, pw, pb, wsb, out);
    } else {
        hipLaunchKernelGGL(fused_gemm<false>, dim3(NWG), dim3(512), 0, stream,
                           x, sh, sw, pw, pb, (const unsigned char*)nullptr, out);
    }
}

// Round 11
// 94.234 us; speedup vs baseline: 1.3883x; 1.2098x over previous
//
#include <hip/hip_runtime.h>

typedef __attribute__((ext_vector_type(8))) short short8;
typedef __attribute__((ext_vector_type(4))) float f32x4;
typedef unsigned int u32;

#define NB 64
#define NC 3
#define NH 384
#define NW 384
#define HW (NH*NW)
#define NPATCH 576
#define NE 768
#define KDIM 768           // NC*16*16
#define MDIM (NB*NPATCH)   // 36864

#define BM 128
#define BN 256
#define BK 64
#define NBLK_N (NE / BN)       // 3
#define NBLK_M (MDIM / BM)     // 288
#define NWG (NBLK_M * NBLK_N)  // 864
#define NKK (KDIM / BK)        // 12

#define TILE_B_BYTES (BN * BK * 2)                 // 32768
#define WS_B_BYTES ((size_t)NBLK_N * NKK * TILE_B_BYTES)   // 1,179,648

#define GLOBAL_AS __attribute__((address_space(1)))
#define LDS_AS    __attribute__((address_space(3)))

__device__ __forceinline__ unsigned short f2bf(float f) {
    unsigned int u = __builtin_bit_cast(unsigned int, f);
    u += 0x7fffu + ((u >> 16) & 1u);   // round-to-nearest-even
    return (unsigned short)(u >> 16);
}

// packed f32x2 -> bf16x2 (RNE), 1 VALU inst (no builtin on gfx950)
__device__ __forceinline__ u32 cvtpk(float lo, float hi) {
    u32 r;
    asm("v_cvt_pk_bf16_f32 %0, %1, %2" : "=v"(r) : "v"(lo), "v"(hi));
    return r;
}

__device__ __forceinline__ void gload_lds16(const void* g, void* l) {
    __builtin_amdgcn_global_load_lds((const GLOBAL_AS u32*)g, (LDS_AS u32*)l, 16, 0, 0);
}

#define SCHED0() __builtin_amdgcn_sched_barrier(0)

// ---- pre-pass: proj_w fp32 [E][K] -> bf16 row-order tile images, XOR
// swizzle baked in. Tile (bn,kk) = 32KB: row r = e&255 (128B), 16B chunk
// ch stored at physical chunk ch^(r&7).
__global__ __launch_bounds__(256) void convert_w_row(
    const float* __restrict__ pw, unsigned char* __restrict__ wsb)
{
    int id = blockIdx.x * 256 + threadIdx.x;   // 768*96 = 73728
    int e  = id / 96;
    int ck = id - e * 96;
    int k0 = ck * 8;

    const float4 f0 = *reinterpret_cast<const float4*>(pw + (size_t)e * KDIM + k0);
    const float4 f1 = *reinterpret_cast<const float4*>(pw + (size_t)e * KDIM + k0 + 4);
    int bn = e >> 8;
    int r  = e & 255;
    int kk = k0 >> 6;
    int ch = (k0 & 63) >> 3;
    size_t off = (size_t)(bn * NKK + kk) * TILE_B_BYTES + r * 128
               + ((ch ^ (r & 7)) * 16);
    *reinterpret_cast<uint4*>(wsb + off) = make_uint4(
        cvtpk(f0.x, f0.y), cvtpk(f0.z, f0.w),
        cvtpk(f1.x, f1.y), cvtpk(f1.z, f1.w));
}

// =====================================================================
// Fused gather-GEMM (R6 structure) with counted-vmcnt barriers:
//   bar1 = lgkmcnt(0) only        (A-gather prefetch stays in flight)
//   bar2 = vmcnt(4) lgkmcnt(0)    (retire B-DMA only; LOADA survives)
// =====================================================================
template <bool WSB>
__global__ __launch_bounds__(512, 4) void fused_gemm(
    const float* __restrict__ x,
    const int* __restrict__ start_h,
    const int* __restrict__ start_w,
    const float* __restrict__ pw,
    const float* __restrict__ pb,
    const unsigned char* __restrict__ wsb,
    float* __restrict__ out)
{
    __shared__ __align__(16) unsigned short lA[2][BM * BK];  // 2 x 16 KB, swizzled
    __shared__ __align__(16) unsigned short lB[BN * BK];     // 32 KB, swizzled
    __shared__ int baseOff[BM];

    const int tid = threadIdx.x;
    const int bid  = blockIdx.x;
    const int lbid = (bid & 7) * (NWG / 8) + (bid >> 3);     // XCD swizzle
    const int bm = lbid / NBLK_N;
    const int bn = lbid - bm * NBLK_N;
    const int m0 = bm * BM;
    const int e0 = bn * BN;

    if (tid < BM) {
        int m = m0 + tid;
        int b = m / NPATCH;
        int n = m - b * NPATCH;
        baseOff[tid] = b * (NC * HW) + start_h[b * NPATCH + n] * NW
                     + start_w[b * NPATCH + n];
    }

    const int lane = tid & 63;
    const int wv   = tid >> 6;       // wave 0..7
    const int wr   = wv >> 2;        // 0..1  (64 m-rows)
    const int wc   = wv & 3;         // 0..3  (64 e-cols)
    const int lr   = lane & 15;
    const int lk   = lane >> 4;      // 0..3

    // A staging decomposition: 16 threads/row, 32 rows/iter, 4 iters
    const int rt = tid >> 4;         // 0..31
    const int j0 = (tid & 15) * 4;   // float index within 64-wide k-slice
    const int chunk  = j0 >> 3;      // 16B chunk in row (0..7)
    const int within = j0 & 7;       // 0 or 4
    const int hsub   = j0 >> 4;      // 0..3
    const int wsub   = j0 & 15;      // 0,4,8,12

    __syncthreads();

    int ab[4];
    #pragma unroll
    for (int i = 0; i < 4; ++i)
        ab[i] = baseOff[i * 32 + rt] + hsub * NW + wsub;

    f32x4 acc[4][4] = {};
    float4 ar[4];

#define LOADA(KK)                                                             \
    {                                                                         \
        const int koff = ((KK) >> 2) * HW + ((KK) & 3) * 4 * NW;              \
        _Pragma("unroll")                                                     \
        for (int i = 0; i < 4; ++i)                                           \
            ar[i] = *reinterpret_cast<const float4*>(x + ab[i] + koff);       \
    }

#define WRITEA(BUF)                                                           \
    {                                                                         \
        _Pragma("unroll")                                                     \
        for (int i = 0; i < 4; ++i) {                                         \
            int r = i * 32 + rt;                                              \
            int off = r * BK + ((chunk ^ (r & 7)) * 8) + within;              \
            *reinterpret_cast<uint2*>(&lA[BUF][off]) =                        \
                make_uint2(cvtpk(ar[i].x, ar[i].y), cvtpk(ar[i].z, ar[i].w)); \
        }                                                                     \
    }

#define STAGEB(KK)                                                            \
    if (WSB) {                                                                \
        const unsigned char* src = wsb + (size_t)(bn * NKK + (KK)) * TILE_B_BYTES \
                                 + wv * 1024 + lane * 16;                     \
        unsigned char* dst = reinterpret_cast<unsigned char*>(lB) + wv * 1024;\
        _Pragma("unroll")                                                     \
        for (int i = 0; i < 4; ++i)                                           \
            gload_lds16(src + i * 8192, dst + i * 8192);                      \
    } else {                                                                  \
        _Pragma("unroll")                                                     \
        for (int i = 0; i < 8; ++i) {                                         \
            int r = i * 32 + rt;                                              \
            const float4 wf = *reinterpret_cast<const float4*>(               \
                pw + (size_t)(e0 + r) * KDIM + (KK) * BK + j0);               \
            int off = r * BK + ((chunk ^ (r & 7)) * 8) + within;              \
            *reinterpret_cast<uint2*>(&lB[off]) =                            \
                make_uint2(cvtpk(wf.x, wf.y), cvtpk(wf.z, wf.w));             \
        }                                                                     \
    }

#define COMPUTE(BUF)                                                          \
    {                                                                         \
        _Pragma("unroll")                                                     \
        for (int ks = 0; ks < 2; ++ks) {                                      \
            short8 af[4], bfr[4];                                             \
            _Pragma("unroll")                                                 \
            for (int mi = 0; mi < 4; ++mi) {                                  \
                int row = wr * 64 + mi * 16 + lr;                             \
                int off = row * BK + (((ks * 4 + lk) ^ (row & 7)) * 8);       \
                af[mi] = *reinterpret_cast<const short8*>(&lA[BUF][off]);     \
            }                                                                 \
            _Pragma("unroll")                                                 \
            for (int ni = 0; ni < 4; ++ni) {                                  \
                int row = wc * 64 + ni * 16 + lr;                             \
                int off = row * BK + (((ks * 4 + lk) ^ (row & 7)) * 8);       \
                bfr[ni] = *reinterpret_cast<const short8*>(&lB[off]);         \
            }                                                                 \
            _Pragma("unroll")                                                 \
            for (int mi = 0; mi < 4; ++mi)                                    \
                _Pragma("unroll")                                             \
                for (int ni = 0; ni < 4; ++ni)                                \
                    acc[mi][ni] = __builtin_amdgcn_mfma_f32_16x16x32_bf16(    \
                        af[mi], bfr[ni], acc[mi][ni], 0, 0, 0);               \
        }                                                                     \
    }

    // -------- prologue: lA[0]<-A(0), lA[1]<-A(1), lB<-B(0), A(2) in flight
    LOADA(0)
    WRITEA(0)                       // compiler-counted vmcnt wait on ar
    LOADA(1)
    WRITEA(1)
    STAGEB(0)                       // 4 DMA
    SCHED0();
    LOADA(2)                        // prefetch, stays in flight across barrier
    SCHED0();
    asm volatile("s_waitcnt vmcnt(4) lgkmcnt(0)" ::: "memory");  // B(0) + A-writes done
    SCHED0();
    __builtin_amdgcn_s_barrier();
    SCHED0();

    for (int kk = 0; kk < NKK; ++kk) {
        const int buf = kk & 1;
        COMPUTE(buf)                              // reads lA[buf] + lB(kk)
        // bar1: all waves done reading lB; A prefetch NOT drained
        asm volatile("s_waitcnt lgkmcnt(0)" ::: "memory");
        SCHED0();
        __builtin_amdgcn_s_barrier();
        SCHED0();
        if (kk + 2 < NKK) WRITEA(buf)             // lA[buf] <- A(kk+2) (aged loads)
        if (kk + 1 < NKK) STAGEB(kk + 1)          // 4 DMA into lB
        SCHED0();                                 // pin: STAGEB older than LOADA
        if (kk + 3 < NKK) LOADA(kk + 3)           // refill ar, stays in flight
        SCHED0();
        if (kk + 1 < NKK) {
            // bar2: retire B-DMA (oldest 4) + publish ds_writes; LOADA survives
            if (kk + 3 < NKK) {
                asm volatile("s_waitcnt vmcnt(4) lgkmcnt(0)" ::: "memory");
            } else {
                asm volatile("s_waitcnt vmcnt(0) lgkmcnt(0)" ::: "memory");
            }
            SCHED0();
            __builtin_amdgcn_s_barrier();
            SCHED0();
        }
    }

#undef LOADA
#undef WRITEA
#undef STAGEB
#undef COMPUTE

    // ---- epilogue: bias + store ----
    float biasv[4];
    #pragma unroll
    for (int ni = 0; ni < 4; ++ni)
        biasv[ni] = pb[e0 + wc * 64 + ni * 16 + lr];

    #pragma unroll
    for (int mi = 0; mi < 4; ++mi) {
        #pragma unroll
        for (int j = 0; j < 4; ++j) {
            int row = m0 + wr * 64 + mi * 16 + lk * 4 + j;
            float* orow = out + (size_t)row * NE + e0 + wc * 64 + lr;
            #pragma unroll
            for (int ni = 0; ni < 4; ++ni)
                orow[ni * 16] = acc[mi][ni][j] + biasv[ni];
        }
    }
}

extern "C" void kernel_launch(void* const* d_in, const int* in_sizes, int n_in,
                              void* d_out, int out_size, void* d_ws, size_t ws_size,
                              hipStream_t stream) {
    const float* x  = (const float*)d_in[0];
    const int* sh   = (const int*)d_in[1];
    const int* sw   = (const int*)d_in[2];
    const float* pw = (const float*)d_in[3];
    const float* pb = (const float*)d_in[4];
    float* out = (float*)d_out;

    if (ws_size >= WS_B_BYTES) {
        unsigned char* wsb = (unsigned char*)d_ws;
        hipLaunchKernelGGL(convert_w_row, dim3(288), dim3(256), 0, stream, pw, wsb);
        hipLaunchKernelGGL(fused_gemm<true>, dim3(NWG), dim3(512), 0, stream,
                           x, sh, sw, pw, pb, wsb, out);
    } else {
        hipLaunchKernelGGL(fused_gemm<false>, dim3(NWG), dim3(512), 0, stream,
                           x, sh, sw, pw, pb, (const unsigned char*)nullptr, out);
    }
}